// Round 10
// baseline (401.910 us; speedup 1.0000x reference)
//
#include <hip/hip_runtime.h>
#include <stdint.h>

// Problem constants
#define NHEAD 12
#define HDIM  64
#define EMB   768
#define N3    2304      // 3*EMB
#define SEQ   2048
#define BATCH 4
#define MROWS 8192      // BATCH*SEQ

// 0.125 * log2(e): folds the 1/sqrt(64) scale AND the e->2 base change into Q.
#define QSCALE 0.18033688011112042f

typedef __bf16 bf16_t;
typedef __bf16 bf16x8 __attribute__((ext_vector_type(8)));
typedef float  f32x4  __attribute__((ext_vector_type(4)));

// async global->LDS, 16 B/lane. HW scatters lane i to (readfirstlane(lds)) + i*16.
__device__ __forceinline__ void gld_lds16(void* lds, const void* g) {
    __builtin_amdgcn_global_load_lds((const __attribute__((address_space(1))) void*)g,
                                     (__attribute__((address_space(3))) void*)lds,
                                     16, 0, 0);
}

// raw v_exp_f32 (2^x): args are provably in-range; skips libm denormal fixup.
__device__ __forceinline__ float fast_exp2(float x) {
    return __builtin_amdgcn_exp2f(x);
}

// ---------------------------------------------------------------------------
// Tiled transpose+convert: W [K][N] fp32 -> WT [N][K] bf16 (dtype proven r3/4).
// ---------------------------------------------------------------------------
__global__ __launch_bounds__(256) void transpose_cvt_k(
    const float* __restrict__ W, bf16_t* __restrict__ WT, int K, int N) {
    __shared__ float tile[32][33];
    const int n0 = blockIdx.x * 32, k0 = blockIdx.y * 32;
    const int tx = threadIdx.x & 31, ty = threadIdx.x >> 5;   // ty 0..7
#pragma unroll
    for (int i = 0; i < 32; i += 8)
        tile[ty + i][tx] = W[(size_t)(k0 + ty + i) * N + (n0 + tx)];
    __syncthreads();
#pragma unroll
    for (int i = 0; i < 32; i += 8)
        WT[(size_t)(n0 + ty + i) * K + (k0 + tx)] = (bf16_t)tile[tx][ty + i];
}

// V transpose: Vb [bh][s][d] -> Vt [bh][d][s], LDS-tiled, both sides coalesced.
__global__ __launch_bounds__(256) void vtrans_k(const bf16_t* __restrict__ Vb,
                                                bf16_t* __restrict__ Vt) {
    __shared__ bf16_t tile[32][33];
    const int bh = blockIdx.z;
    const int s0 = blockIdx.y * 32;
    const int d0 = blockIdx.x * 32;
    const int tx = threadIdx.x & 31, ty = threadIdx.x >> 5;   // ty 0..7
    const bf16_t* src = Vb + ((size_t)bh * SEQ + s0) * HDIM + d0;
#pragma unroll
    for (int i = 0; i < 32; i += 8)
        tile[ty + i][tx] = src[(size_t)(ty + i) * HDIM + tx];
    __syncthreads();
    bf16_t* dst = Vt + ((size_t)bh * HDIM + d0) * SEQ + s0;
#pragma unroll
    for (int i = 0; i < 32; i += 8)
        dst[(size_t)(ty + i) * SEQ + tx] = tile[tx][ty + i];
}

// ---------------------------------------------------------------------------
// GEMM (unchanged from round 9): C[M][N] = A[M][K=768] * BT[N][K]^T + bias.
// MODE 1 (QKV): A fp32 ingest (register convert), B via global_load_lds;
//               bf16 [bh][s][d] out; Q pre-scaled by QSCALE.
// MODE 0 (proj): A bf16 via global_load_lds; fp32 out.
// ---------------------------------------------------------------------------
template<int MODE>
__global__ __launch_bounds__(256) void gemm_kernel(
    const void* __restrict__ Av,
    const bf16_t* __restrict__ BT,
    const float* __restrict__ bias,
    float* __restrict__ out,
    bf16_t* __restrict__ qbuf,
    bf16_t* __restrict__ kbuf,
    bf16_t* __restrict__ vbuf,
    int Ncols)
{
    const int K = 768;
    __shared__ alignas(16) bf16_t As[2][128 * 32];
    __shared__ alignas(16) bf16_t Bs[2][128 * 32];

    const int tid    = threadIdx.x;
    const int wave   = tid >> 6;
    const int lane   = tid & 63;
    const int lane15 = lane & 15;
    const int quad   = lane >> 4;

    const int mBase = blockIdx.y * 128;
    const int nBase = blockIdx.x * 128;
    const int wm = (wave >> 1) * 64;
    const int wn = (wave & 1) * 64;

    f32x4 acc[4][4];
#pragma unroll
    for (int i = 0; i < 4; i++)
#pragma unroll
        for (int j = 0; j < 4; j++) acc[i][j] = (f32x4){0.f, 0.f, 0.f, 0.f};

    const bf16_t* bSrc = BT + (size_t)nBase * K;

    const int srow = lane >> 2;      // 0..15 within 16-row group
    const int sch  = lane & 3;       // physical chunk this lane fills

    auto issueB = [&](int k0, int buf) {
#pragma unroll
        for (int p = 0; p < 2; p++) {
            int r0  = p * 64 + wave * 16;          // wave-uniform
            int row = r0 + srow;
            int lch = sch ^ (row & 3);             // logical chunk to fetch
            gld_lds16(&Bs[buf][r0 * 32], bSrc + (size_t)row * K + k0 + lch * 8);
        }
    };

    const int arow  = tid >> 1;          // 0..127
    const int ahalf = tid & 1;           // 16-col half
    float4 afr[4];
    const float*  aSrcF = (MODE == 1) ? (const float*)Av + (size_t)mBase * K : nullptr;
    const bf16_t* aSrcB = (MODE == 0) ? (const bf16_t*)Av + (size_t)mBase * K : nullptr;

    auto loadA = [&](int k0) {
        if (MODE == 1) {
            const float* p = aSrcF + (size_t)arow * K + k0 + ahalf * 16;
#pragma unroll
            for (int q = 0; q < 4; q++) afr[q] = *(const float4*)(p + q * 4);
        }
    };
    auto writeA = [&](int buf) {
#pragma unroll
        for (int c = 0; c < 2; c++) {
            bf16x8 v;
#pragma unroll
            for (int e = 0; e < 8; e++) {
                float f = (e < 4) ? ((const float*)&afr[c * 2])[e]
                                  : ((const float*)&afr[c * 2 + 1])[e - 4];
                v[e] = (bf16_t)f;
            }
            int lch = ahalf * 2 + c;
            *(bf16x8*)&As[buf][arow * 32 + (lch ^ (arow & 3)) * 8] = v;
        }
    };
    auto issueA0 = [&](int k0, int buf) {
#pragma unroll
        for (int p = 0; p < 2; p++) {
            int r0  = p * 64 + wave * 16;
            int row = r0 + srow;
            int lch = sch ^ (row & 3);
            gld_lds16(&As[buf][r0 * 32], aSrcB + (size_t)row * K + k0 + lch * 8);
        }
    };

    if (MODE == 1) { loadA(0); issueB(0, 0); writeA(0); }
    else           { issueA0(0, 0); issueB(0, 0); }

    for (int k0 = 0, it = 0; k0 < K; k0 += 32, it++) {
        const int buf = it & 1;
        __syncthreads();
        const bool more = (k0 + 32 < K);
        if (more) {
            issueB(k0 + 32, buf ^ 1);
            if (MODE == 1) loadA(k0 + 32); else issueA0(k0 + 32, buf ^ 1);
        }

        bf16x8 aF[4], bF[4];
#pragma unroll
        for (int t = 0; t < 4; t++) {
            int ra = wm + t * 16 + lane15;
            int rb = wn + t * 16 + lane15;
            aF[t] = *(const bf16x8*)&As[buf][ra * 32 + (quad ^ (ra & 3)) * 8];
            bF[t] = *(const bf16x8*)&Bs[buf][rb * 32 + (quad ^ (rb & 3)) * 8];
        }
#pragma unroll
        for (int i = 0; i < 4; i++)
#pragma unroll
            for (int j = 0; j < 4; j++)
                acc[i][j] = __builtin_amdgcn_mfma_f32_16x16x32_bf16(aF[i], bF[j], acc[i][j], 0, 0, 0);

        if (MODE == 1 && more) writeA(buf ^ 1);
    }

    const int region = (MODE == 1) ? (nBase / EMB) : 0;
    bf16_t* dst = nullptr;
    float scale = 1.0f;
    if (MODE == 1) {
        dst = (region == 0) ? qbuf : (region == 1 ? kbuf : vbuf);
        if (region == 0) scale = QSCALE;
    }
#pragma unroll
    for (int i = 0; i < 4; i++) {
#pragma unroll
        for (int j = 0; j < 4; j++) {
            int gn = nBase + wn + j * 16 + lane15;
            float bv = bias[gn];
#pragma unroll
            for (int r = 0; r < 4; r++) {
                int gm = mBase + wm + i * 16 + quad * 4 + r;
                float v = acc[i][j][r] + bv;
                if (MODE == 0) {
                    out[(size_t)gm * Ncols + gn] = v;      // FP32 store
                } else {
                    int b = gm >> 11, s = gm & 2047;
                    int within = gn - region * EMB;
                    int h = within >> 6, d = within & 63;
                    int bh = b * NHEAD + h;
                    dst[((size_t)bh * SEQ + s) * HDIM + d] = (bf16_t)(v * scale);
                }
            }
        }
    }
}

// ---------------------------------------------------------------------------
// Flash attention, causal — round 10: r8 structure (paired {j,31-j} segments,
// 33 uniform tiles/block) + LDS DIET for occupancy: only K is LDS-staged
// (dbuf 16 KB); V reads go back to per-wave global bf16x8 loads (r5-style —
// cache hierarchy absorbed the 4x wave redundancy fine, r5 FETCH == r8 FETCH).
// LDS 25.6 KB -> 6 blocks/CU (was 3). exp2 via raw v_exp_f32.
// Unnormalized exp2 softmax (r8). Diagonal-only masks. launch_bounds(256,6).
// ---------------------------------------------------------------------------
__global__ __launch_bounds__(256, 6) void attn_kernel(
    const bf16_t* __restrict__ qbuf,
    const bf16_t* __restrict__ kbuf,
    const bf16_t* __restrict__ vtbuf,
    bf16_t* __restrict__ obuf)
{
    __shared__ alignas(16) bf16_t Ks[2][64 * 64];     // [key][dim], dbuf, 16 KB
    __shared__ alignas(16) bf16_t Plds[4][16 * 72];   // per-wave, 9.2 KB

    const int tid    = threadIdx.x;
    const int wave   = tid >> 6;
    const int lane   = tid & 63;
    const int lane15 = lane & 15;
    const int quad   = lane >> 4;

    const int bh = blockIdx.x >> 4;
    const int j  = blockIdx.x & 15;

    const bf16_t* Qp = qbuf  + (size_t)bh * SEQ * HDIM;
    const bf16_t* Kp = kbuf  + (size_t)bh * SEQ * HDIM;
    const bf16_t* Vp = vtbuf + (size_t)bh * HDIM * SEQ;
    bf16_t* pl = &Plds[wave][0];
    const int b = bh / NHEAD, h = bh % NHEAD;

    const int srow8 = lane >> 3;   // 0..7 within 8-row group
    const int sch8  = lane & 7;    // physical chunk this lane fills

    auto issueK = [&](int kb, int buf) {
#pragma unroll
        for (int p = 0; p < 2; p++) {
            int r0  = p * 32 + wave * 8;             // wave-uniform
            int row = r0 + srow8;
            int lch = sch8 ^ (row & 7);              // logical chunk to fetch
            gld_lds16(&Ks[buf][r0 * 64], Kp + (size_t)(kb + row) * HDIM + lch * 8);
        }
    };

    for (int seg = 0; seg < 2; seg++) {
        const int qt    = seg ? (31 - j) : j;
        const int qBase = qt * 64;
        const int q0    = qBase + wave * 16;

        const bf16x8 qf0 = *(const bf16x8*)&Qp[(size_t)(q0 + lane15) * HDIM + quad * 8];
        const bf16x8 qf1 = *(const bf16x8*)&Qp[(size_t)(q0 + lane15) * HDIM + 32 + quad * 8];

        float lrow[4];
        f32x4 oacc[4];
#pragma unroll
        for (int r = 0; r < 4; r++) lrow[r] = 0.f;
#pragma unroll
        for (int t = 0; t < 4; t++) oacc[t] = (f32x4){0.f, 0.f, 0.f, 0.f};

        const int nT = qt + 1;    // 64-key tiles
        __syncthreads();          // protect K buffers from previous seg's readers
        issueK(0, 0);

        for (int kt = 0; kt < nT; kt++) {
            const int buf = kt & 1;
            __syncthreads();                                  // K tile kt ready
            if (kt + 1 < nT) issueK((kt + 1) * 64, buf ^ 1);  // prefetch

            const int kb = kt * 64;

            // V global loads issued early (latency hidden by 24 waves/CU + MFMA phase)
            bf16x8 vB0[4], vB1[4];
#pragma unroll
            for (int t = 0; t < 4; t++) {
                const bf16_t* vrow = &Vp[(size_t)(t * 16 + lane15) * SEQ + kb];
                vB0[t] = *(const bf16x8*)&vrow[quad * 8];
                vB1[t] = *(const bf16x8*)&vrow[32 + quad * 8];
            }

            // QK^T from LDS: 16q x 64k (scores already in log2 domain)
            f32x4 s[4];
#pragma unroll
            for (int kg = 0; kg < 4; kg++) {
                s[kg] = (f32x4){0.f, 0.f, 0.f, 0.f};
                int row = kg * 16 + lane15;
                bf16x8 kf0 = *(const bf16x8*)&Ks[buf][row * 64 + ((quad    ) ^ (row & 7)) * 8];
                bf16x8 kf1 = *(const bf16x8*)&Ks[buf][row * 64 + ((quad + 4) ^ (row & 7)) * 8];
                s[kg] = __builtin_amdgcn_mfma_f32_16x16x32_bf16(qf0, kf0, s[kg], 0, 0, 0);
                s[kg] = __builtin_amdgcn_mfma_f32_16x16x32_bf16(qf1, kf1, s[kg], 0, 0, 0);
            }

            // causal mask: only the diagonal tile needs it (wave-uniform test)
            if (kb + 64 > q0) {
#pragma unroll
                for (int kg = 0; kg < 4; kg++) {
                    int key = kb + kg * 16 + lane15;
#pragma unroll
                    for (int r = 0; r < 4; r++) {
                        int qrow = q0 + quad * 4 + r;
                        s[kg][r] = (key <= qrow) ? s[kg][r] : -1e30f;
                    }
                }
            }

            // unnormalized softmax: P = exp2(s), l += sum
#pragma unroll
            for (int kg = 0; kg < 4; kg++)
#pragma unroll
                for (int r = 0; r < 4; r++)
                    s[kg][r] = fast_exp2(s[kg][r]);

#pragma unroll
            for (int r = 0; r < 4; r++)
                lrow[r] += (s[0][r] + s[1][r]) + (s[2][r] + s[3][r]);

            // P: C-layout -> wave-private LDS -> A-layout (no barrier needed)
#pragma unroll
            for (int kg = 0; kg < 4; kg++)
#pragma unroll
                for (int r = 0; r < 4; r++)
                    pl[(quad * 4 + r) * 72 + kg * 16 + lane15] = (bf16_t)s[kg][r];

            bf16x8 pA0 = *(const bf16x8*)&pl[lane15 * 72 + quad * 8];
            bf16x8 pA1 = *(const bf16x8*)&pl[lane15 * 72 + 32 + quad * 8];

            // PV: O[16q][64d] += P[16x64] * V[64k x 64d]
#pragma unroll
            for (int t = 0; t < 4; t++) {
                oacc[t] = __builtin_amdgcn_mfma_f32_16x16x32_bf16(pA0, vB0[t], oacc[t], 0, 0, 0);
                oacc[t] = __builtin_amdgcn_mfma_f32_16x16x32_bf16(pA1, vB1[t], oacc[t], 0, 0, 0);
            }
        }

        // reduce per-lane partial l across the 16 lanes (once per q-tile)
#pragma unroll
        for (int off = 8; off >= 1; off >>= 1)
#pragma unroll
            for (int r = 0; r < 4; r++) lrow[r] += __shfl_xor(lrow[r], off, 64);

        float inv_l[4];
#pragma unroll
        for (int r = 0; r < 4; r++) inv_l[r] = 1.0f / lrow[r];
#pragma unroll
        for (int t = 0; t < 4; t++) {
#pragma unroll
            for (int r = 0; r < 4; r++) {
                int s2 = q0 + quad * 4 + r;
                int d  = t * 16 + lane15;
                obuf[((size_t)(b * SEQ + s2)) * EMB + h * HDIM + d] = (bf16_t)(oacc[t][r] * inv_l[r]);
            }
        }
    }
}

// ---------------------------------------------------------------------------
extern "C" void kernel_launch(void* const* d_in, const int* in_sizes, int n_in,
                              void* d_out, int out_size, void* d_ws, size_t ws_size,
                              hipStream_t stream) {
    const float* x      = (const float*)d_in[0];
    // d_in[1] = mask: causal by construction, implemented analytically
    const float* W_attn = (const float*)d_in[2];
    const float* b_attn = (const float*)d_in[3];
    const float* W_proj = (const float*)d_in[4];
    const float* b_proj = (const float*)d_in[5];
    float* out = (float*)d_out;   // fp32 output (proven r4)

    bf16_t* ws  = (bf16_t*)d_ws;
    bf16_t* WaT = ws;                                         // [2304][768]
    bf16_t* WpT = WaT + (size_t)N3 * EMB;                     // [768][768]
    bf16_t* Qb  = WpT + (size_t)EMB * EMB;                    // [B*H][S][D]
    bf16_t* Kb  = Qb + (size_t)BATCH * NHEAD * SEQ * HDIM;
    bf16_t* Vt  = Kb + (size_t)BATCH * NHEAD * SEQ * HDIM;    // [B*H][D][S]
    bf16_t* Ob  = Vt + (size_t)BATCH * NHEAD * SEQ * HDIM;    // [8192][768]
    bf16_t* Vb  = Ob;   // alias: V [bh][s][d] staging dead before attn writes Ob

    transpose_cvt_k<<<dim3(N3 / 32, EMB / 32), 256, 0, stream>>>(W_attn, WaT, EMB, N3);
    transpose_cvt_k<<<dim3(EMB / 32, EMB / 32), 256, 0, stream>>>(W_proj, WpT, EMB, EMB);

    gemm_kernel<1><<<dim3(N3 / 128, MROWS / 128), 256, 0, stream>>>(
        x, WaT, b_attn, nullptr, Qb, Kb, Vb, N3);

    vtrans_k<<<dim3(HDIM / 32, SEQ / 32, BATCH * NHEAD), 256, 0, stream>>>(Vb, Vt);

    attn_kernel<<<BATCH * NHEAD * 16, 256, 0, stream>>>(Qb, Kb, Vt, Ob);

    gemm_kernel<0><<<dim3(EMB / 128, MROWS / 128), 256, 0, stream>>>(
        Ob, WpT, b_proj, out, nullptr, nullptr, nullptr, EMB);
}

// Round 11
// 395.695 us; speedup vs baseline: 1.0157x; 1.0157x over previous
//
#include <hip/hip_runtime.h>
#include <stdint.h>

// Problem constants
#define NHEAD 12
#define HDIM  64
#define EMB   768
#define N3    2304      // 3*EMB
#define SEQ   2048
#define BATCH 4
#define MROWS 8192      // BATCH*SEQ

// 0.125 * log2(e): folds the 1/sqrt(64) scale AND the e->2 base change into Q.
#define QSCALE 0.18033688011112042f

typedef __bf16 bf16_t;
typedef __bf16 bf16x8 __attribute__((ext_vector_type(8)));
typedef float  f32x4  __attribute__((ext_vector_type(4)));

// async global->LDS, 16 B/lane. HW scatters lane i to (readfirstlane(lds)) + i*16.
__device__ __forceinline__ void gld_lds16(void* lds, const void* g) {
    __builtin_amdgcn_global_load_lds((const __attribute__((address_space(1))) void*)g,
                                     (__attribute__((address_space(3))) void*)lds,
                                     16, 0, 0);
}

// raw v_exp_f32 (2^x): args are provably in-range; skips libm denormal fixup.
__device__ __forceinline__ float fast_exp2(float x) {
    return __builtin_amdgcn_exp2f(x);
}

// ---------------------------------------------------------------------------
// Tiled transpose+convert: W [K][N] fp32 -> WT [N][K] bf16 (dtype proven r3/4).
// ---------------------------------------------------------------------------
__global__ __launch_bounds__(256) void transpose_cvt_k(
    const float* __restrict__ W, bf16_t* __restrict__ WT, int K, int N) {
    __shared__ float tile[32][33];
    const int n0 = blockIdx.x * 32, k0 = blockIdx.y * 32;
    const int tx = threadIdx.x & 31, ty = threadIdx.x >> 5;   // ty 0..7
#pragma unroll
    for (int i = 0; i < 32; i += 8)
        tile[ty + i][tx] = W[(size_t)(k0 + ty + i) * N + (n0 + tx)];
    __syncthreads();
#pragma unroll
    for (int i = 0; i < 32; i += 8)
        WT[(size_t)(n0 + ty + i) * K + (k0 + tx)] = (bf16_t)tile[tx][ty + i];
}

// V transpose: Vb [bh][s][d] -> Vt [bh][d][s], LDS-tiled, both sides coalesced.
__global__ __launch_bounds__(256) void vtrans_k(const bf16_t* __restrict__ Vb,
                                                bf16_t* __restrict__ Vt) {
    __shared__ bf16_t tile[32][33];
    const int bh = blockIdx.z;
    const int s0 = blockIdx.y * 32;
    const int d0 = blockIdx.x * 32;
    const int tx = threadIdx.x & 31, ty = threadIdx.x >> 5;   // ty 0..7
    const bf16_t* src = Vb + ((size_t)bh * SEQ + s0) * HDIM + d0;
#pragma unroll
    for (int i = 0; i < 32; i += 8)
        tile[ty + i][tx] = src[(size_t)(ty + i) * HDIM + tx];
    __syncthreads();
    bf16_t* dst = Vt + ((size_t)bh * HDIM + d0) * SEQ + s0;
#pragma unroll
    for (int i = 0; i < 32; i += 8)
        dst[(size_t)(ty + i) * SEQ + tx] = tile[tx][ty + i];
}

// ---------------------------------------------------------------------------
// GEMM (unchanged from round 9): C[M][N] = A[M][K=768] * BT[N][K]^T + bias.
// MODE 1 (QKV): A fp32 ingest (register convert), B via global_load_lds;
//               bf16 [bh][s][d] out; Q pre-scaled by QSCALE.
// MODE 0 (proj): A bf16 via global_load_lds; fp32 out.
// ---------------------------------------------------------------------------
template<int MODE>
__global__ __launch_bounds__(256) void gemm_kernel(
    const void* __restrict__ Av,
    const bf16_t* __restrict__ BT,
    const float* __restrict__ bias,
    float* __restrict__ out,
    bf16_t* __restrict__ qbuf,
    bf16_t* __restrict__ kbuf,
    bf16_t* __restrict__ vbuf,
    int Ncols)
{
    const int K = 768;
    __shared__ alignas(16) bf16_t As[2][128 * 32];
    __shared__ alignas(16) bf16_t Bs[2][128 * 32];

    const int tid    = threadIdx.x;
    const int wave   = tid >> 6;
    const int lane   = tid & 63;
    const int lane15 = lane & 15;
    const int quad   = lane >> 4;

    const int mBase = blockIdx.y * 128;
    const int nBase = blockIdx.x * 128;
    const int wm = (wave >> 1) * 64;
    const int wn = (wave & 1) * 64;

    f32x4 acc[4][4];
#pragma unroll
    for (int i = 0; i < 4; i++)
#pragma unroll
        for (int j = 0; j < 4; j++) acc[i][j] = (f32x4){0.f, 0.f, 0.f, 0.f};

    const bf16_t* bSrc = BT + (size_t)nBase * K;

    const int srow = lane >> 2;      // 0..15 within 16-row group
    const int sch  = lane & 3;       // physical chunk this lane fills

    auto issueB = [&](int k0, int buf) {
#pragma unroll
        for (int p = 0; p < 2; p++) {
            int r0  = p * 64 + wave * 16;          // wave-uniform
            int row = r0 + srow;
            int lch = sch ^ (row & 3);             // logical chunk to fetch
            gld_lds16(&Bs[buf][r0 * 32], bSrc + (size_t)row * K + k0 + lch * 8);
        }
    };

    const int arow  = tid >> 1;          // 0..127
    const int ahalf = tid & 1;           // 16-col half
    float4 afr[4];
    const float*  aSrcF = (MODE == 1) ? (const float*)Av + (size_t)mBase * K : nullptr;
    const bf16_t* aSrcB = (MODE == 0) ? (const bf16_t*)Av + (size_t)mBase * K : nullptr;

    auto loadA = [&](int k0) {
        if (MODE == 1) {
            const float* p = aSrcF + (size_t)arow * K + k0 + ahalf * 16;
#pragma unroll
            for (int q = 0; q < 4; q++) afr[q] = *(const float4*)(p + q * 4);
        }
    };
    auto writeA = [&](int buf) {
#pragma unroll
        for (int c = 0; c < 2; c++) {
            bf16x8 v;
#pragma unroll
            for (int e = 0; e < 8; e++) {
                float f = (e < 4) ? ((const float*)&afr[c * 2])[e]
                                  : ((const float*)&afr[c * 2 + 1])[e - 4];
                v[e] = (bf16_t)f;
            }
            int lch = ahalf * 2 + c;
            *(bf16x8*)&As[buf][arow * 32 + (lch ^ (arow & 3)) * 8] = v;
        }
    };
    auto issueA0 = [&](int k0, int buf) {
#pragma unroll
        for (int p = 0; p < 2; p++) {
            int r0  = p * 64 + wave * 16;
            int row = r0 + srow;
            int lch = sch ^ (row & 3);
            gld_lds16(&As[buf][r0 * 32], aSrcB + (size_t)row * K + k0 + lch * 8);
        }
    };

    if (MODE == 1) { loadA(0); issueB(0, 0); writeA(0); }
    else           { issueA0(0, 0); issueB(0, 0); }

    for (int k0 = 0, it = 0; k0 < K; k0 += 32, it++) {
        const int buf = it & 1;
        __syncthreads();
        const bool more = (k0 + 32 < K);
        if (more) {
            issueB(k0 + 32, buf ^ 1);
            if (MODE == 1) loadA(k0 + 32); else issueA0(k0 + 32, buf ^ 1);
        }

        bf16x8 aF[4], bF[4];
#pragma unroll
        for (int t = 0; t < 4; t++) {
            int ra = wm + t * 16 + lane15;
            int rb = wn + t * 16 + lane15;
            aF[t] = *(const bf16x8*)&As[buf][ra * 32 + (quad ^ (ra & 3)) * 8];
            bF[t] = *(const bf16x8*)&Bs[buf][rb * 32 + (quad ^ (rb & 3)) * 8];
        }
#pragma unroll
        for (int i = 0; i < 4; i++)
#pragma unroll
            for (int j = 0; j < 4; j++)
                acc[i][j] = __builtin_amdgcn_mfma_f32_16x16x32_bf16(aF[i], bF[j], acc[i][j], 0, 0, 0);

        if (MODE == 1 && more) writeA(buf ^ 1);
    }

    const int region = (MODE == 1) ? (nBase / EMB) : 0;
    bf16_t* dst = nullptr;
    float scale = 1.0f;
    if (MODE == 1) {
        dst = (region == 0) ? qbuf : (region == 1 ? kbuf : vbuf);
        if (region == 0) scale = QSCALE;
    }
#pragma unroll
    for (int i = 0; i < 4; i++) {
#pragma unroll
        for (int j = 0; j < 4; j++) {
            int gn = nBase + wn + j * 16 + lane15;
            float bv = bias[gn];
#pragma unroll
            for (int r = 0; r < 4; r++) {
                int gm = mBase + wm + i * 16 + quad * 4 + r;
                float v = acc[i][j][r] + bv;
                if (MODE == 0) {
                    out[(size_t)gm * Ncols + gn] = v;      // FP32 store
                } else {
                    int b = gm >> 11, s = gm & 2047;
                    int within = gn - region * EMB;
                    int h = within >> 6, d = within & 63;
                    int bh = b * NHEAD + h;
                    dst[((size_t)bh * SEQ + s) * HDIM + d] = (bf16_t)(v * scale);
                }
            }
        }
    }
}

// ---------------------------------------------------------------------------
// Flash attention, causal — round 11: occupancy fix done right.
//  * grid 1536: ONE 64-query tile per block (r8's paired grid of 768 was a
//    hard 3-blocks/CU cap). Blocks ordered big-first per bh (tail = tiny).
//  * V per-wave global loads (r10 idea); LDS = Ks dbuf 16K + P 9.2K = 25.6 KB.
//  * launch_bounds(256,4): VGPR cap 128 >= ~100 natural need -> NO SPILLS
//    (r10's (256,6) forced 40 VGPRs -> 280 MB scratch traffic, the regression).
//  * K via global_load_lds dbuf prefetch; unnormalized exp2 softmax (r8);
//    diagonal-only mask; P round-trip wave-private (no barrier).
// ---------------------------------------------------------------------------
__global__ __launch_bounds__(256, 4) void attn_kernel(
    const bf16_t* __restrict__ qbuf,
    const bf16_t* __restrict__ kbuf,
    const bf16_t* __restrict__ vtbuf,
    bf16_t* __restrict__ obuf)
{
    __shared__ alignas(16) bf16_t Ks[2][64 * 64];     // [key][dim], dbuf, 16 KB
    __shared__ alignas(16) bf16_t Plds[4][16 * 72];   // per-wave, 9.2 KB

    const int tid    = threadIdx.x;
    const int wave   = tid >> 6;
    const int lane   = tid & 63;
    const int lane15 = lane & 15;
    const int quad   = lane >> 4;

    const int bh = blockIdx.x >> 5;
    const int qt = 31 - (blockIdx.x & 31);   // descending: big blocks dispatch first

    const bf16_t* Qp = qbuf  + (size_t)bh * SEQ * HDIM;
    const bf16_t* Kp = kbuf  + (size_t)bh * SEQ * HDIM;
    const bf16_t* Vp = vtbuf + (size_t)bh * HDIM * SEQ;
    bf16_t* pl = &Plds[wave][0];
    const int b = bh / NHEAD, h = bh % NHEAD;

    const int srow8 = lane >> 3;   // 0..7 within 8-row group
    const int sch8  = lane & 7;    // physical chunk this lane fills

    auto issueK = [&](int kb, int buf) {
#pragma unroll
        for (int p = 0; p < 2; p++) {
            int r0  = p * 32 + wave * 8;             // wave-uniform
            int row = r0 + srow8;
            int lch = sch8 ^ (row & 7);              // logical chunk to fetch
            gld_lds16(&Ks[buf][r0 * 64], Kp + (size_t)(kb + row) * HDIM + lch * 8);
        }
    };

    const int q0 = qt * 64 + wave * 16;

    const bf16x8 qf0 = *(const bf16x8*)&Qp[(size_t)(q0 + lane15) * HDIM + quad * 8];
    const bf16x8 qf1 = *(const bf16x8*)&Qp[(size_t)(q0 + lane15) * HDIM + 32 + quad * 8];

    float lrow[4];
    f32x4 oacc[4];
#pragma unroll
    for (int r = 0; r < 4; r++) lrow[r] = 0.f;
#pragma unroll
    for (int t = 0; t < 4; t++) oacc[t] = (f32x4){0.f, 0.f, 0.f, 0.f};

    const int nT = qt + 1;    // 64-key tiles
    issueK(0, 0);

    for (int kt = 0; kt < nT; kt++) {
        const int buf = kt & 1;
        __syncthreads();                                  // K tile kt ready
        if (kt + 1 < nT) issueK((kt + 1) * 64, buf ^ 1);  // prefetch

        const int kb = kt * 64;

        // V global loads issued early (latency hidden by 16 waves/CU + MFMA phase)
        bf16x8 vB0[4], vB1[4];
#pragma unroll
        for (int t = 0; t < 4; t++) {
            const bf16_t* vrow = &Vp[(size_t)(t * 16 + lane15) * SEQ + kb];
            vB0[t] = *(const bf16x8*)&vrow[quad * 8];
            vB1[t] = *(const bf16x8*)&vrow[32 + quad * 8];
        }

        // QK^T from LDS: 16q x 64k (scores already in log2 domain)
        f32x4 s[4];
#pragma unroll
        for (int kg = 0; kg < 4; kg++) {
            s[kg] = (f32x4){0.f, 0.f, 0.f, 0.f};
            int row = kg * 16 + lane15;
            bf16x8 kf0 = *(const bf16x8*)&Ks[buf][row * 64 + ((quad    ) ^ (row & 7)) * 8];
            bf16x8 kf1 = *(const bf16x8*)&Ks[buf][row * 64 + ((quad + 4) ^ (row & 7)) * 8];
            s[kg] = __builtin_amdgcn_mfma_f32_16x16x32_bf16(qf0, kf0, s[kg], 0, 0, 0);
            s[kg] = __builtin_amdgcn_mfma_f32_16x16x32_bf16(qf1, kf1, s[kg], 0, 0, 0);
        }

        // causal mask: only the diagonal tile needs it (wave-uniform test)
        if (kb + 64 > q0) {
#pragma unroll
            for (int kg = 0; kg < 4; kg++) {
                int key = kb + kg * 16 + lane15;
#pragma unroll
                for (int r = 0; r < 4; r++) {
                    int qrow = q0 + quad * 4 + r;
                    s[kg][r] = (key <= qrow) ? s[kg][r] : -1e30f;
                }
            }
        }

        // unnormalized softmax: P = exp2(s), l += sum
#pragma unroll
        for (int kg = 0; kg < 4; kg++)
#pragma unroll
            for (int r = 0; r < 4; r++)
                s[kg][r] = fast_exp2(s[kg][r]);

#pragma unroll
        for (int r = 0; r < 4; r++)
            lrow[r] += (s[0][r] + s[1][r]) + (s[2][r] + s[3][r]);

        // P: C-layout -> wave-private LDS -> A-layout (no barrier needed)
#pragma unroll
        for (int kg = 0; kg < 4; kg++)
#pragma unroll
            for (int r = 0; r < 4; r++)
                pl[(quad * 4 + r) * 72 + kg * 16 + lane15] = (bf16_t)s[kg][r];

        bf16x8 pA0 = *(const bf16x8*)&pl[lane15 * 72 + quad * 8];
        bf16x8 pA1 = *(const bf16x8*)&pl[lane15 * 72 + 32 + quad * 8];

        // PV: O[16q][64d] += P[16x64] * V[64k x 64d]
#pragma unroll
        for (int t = 0; t < 4; t++) {
            oacc[t] = __builtin_amdgcn_mfma_f32_16x16x32_bf16(pA0, vB0[t], oacc[t], 0, 0, 0);
            oacc[t] = __builtin_amdgcn_mfma_f32_16x16x32_bf16(pA1, vB1[t], oacc[t], 0, 0, 0);
        }
    }

    // reduce per-lane partial l across the 16 lanes (once per q-tile)
#pragma unroll
    for (int off = 8; off >= 1; off >>= 1)
#pragma unroll
        for (int r = 0; r < 4; r++) lrow[r] += __shfl_xor(lrow[r], off, 64);

    float inv_l[4];
#pragma unroll
    for (int r = 0; r < 4; r++) inv_l[r] = 1.0f / lrow[r];
#pragma unroll
    for (int t = 0; t < 4; t++) {
#pragma unroll
        for (int r = 0; r < 4; r++) {
            int s2 = q0 + quad * 4 + r;
            int d  = t * 16 + lane15;
            obuf[((size_t)(b * SEQ + s2)) * EMB + h * HDIM + d] = (bf16_t)(oacc[t][r] * inv_l[r]);
        }
    }
}

// ---------------------------------------------------------------------------
extern "C" void kernel_launch(void* const* d_in, const int* in_sizes, int n_in,
                              void* d_out, int out_size, void* d_ws, size_t ws_size,
                              hipStream_t stream) {
    const float* x      = (const float*)d_in[0];
    // d_in[1] = mask: causal by construction, implemented analytically
    const float* W_attn = (const float*)d_in[2];
    const float* b_attn = (const float*)d_in[3];
    const float* W_proj = (const float*)d_in[4];
    const float* b_proj = (const float*)d_in[5];
    float* out = (float*)d_out;   // fp32 output (proven r4)

    bf16_t* ws  = (bf16_t*)d_ws;
    bf16_t* WaT = ws;                                         // [2304][768]
    bf16_t* WpT = WaT + (size_t)N3 * EMB;                     // [768][768]
    bf16_t* Qb  = WpT + (size_t)EMB * EMB;                    // [B*H][S][D]
    bf16_t* Kb  = Qb + (size_t)BATCH * NHEAD * SEQ * HDIM;
    bf16_t* Vt  = Kb + (size_t)BATCH * NHEAD * SEQ * HDIM;    // [B*H][D][S]
    bf16_t* Ob  = Vt + (size_t)BATCH * NHEAD * SEQ * HDIM;    // [8192][768]
    bf16_t* Vb  = Ob;   // alias: V [bh][s][d] staging dead before attn writes Ob

    transpose_cvt_k<<<dim3(N3 / 32, EMB / 32), 256, 0, stream>>>(W_attn, WaT, EMB, N3);
    transpose_cvt_k<<<dim3(EMB / 32, EMB / 32), 256, 0, stream>>>(W_proj, WpT, EMB, EMB);

    gemm_kernel<1><<<dim3(N3 / 128, MROWS / 128), 256, 0, stream>>>(
        x, WaT, b_attn, nullptr, Qb, Kb, Vb, N3);

    vtrans_k<<<dim3(HDIM / 32, SEQ / 32, BATCH * NHEAD), 256, 0, stream>>>(Vb, Vt);

    attn_kernel<<<BATCH * NHEAD * 32, 256, 0, stream>>>(Qb, Kb, Vt, Ob);

    gemm_kernel<0><<<dim3(EMB / 128, MROWS / 128), 256, 0, stream>>>(
        Ob, WpT, b_proj, out, nullptr, nullptr, nullptr, EMB);
}

// Round 12
// 260.486 us; speedup vs baseline: 1.5429x; 1.5191x over previous
//
#include <hip/hip_runtime.h>
#include <stdint.h>

// Problem constants
#define NHEAD 12
#define HDIM  64
#define EMB   768
#define N3    2304      // 3*EMB
#define SEQ   2048
#define BATCH 4
#define MROWS 8192      // BATCH*SEQ

// 0.125 * log2(e): folds the 1/sqrt(64) scale AND the e->2 base change into Q.
#define QSCALE 0.18033688011112042f

typedef __bf16 bf16_t;
typedef __bf16 bf16x8 __attribute__((ext_vector_type(8)));
typedef __bf16 bf16x4 __attribute__((ext_vector_type(4)));
typedef short  s16x4  __attribute__((ext_vector_type(4)));
typedef float  f32x4  __attribute__((ext_vector_type(4)));

// async global->LDS, 16 B/lane. HW scatters lane i to (readfirstlane(lds)) + i*16.
__device__ __forceinline__ void gld_lds16(void* lds, const void* g) {
    __builtin_amdgcn_global_load_lds((const __attribute__((address_space(1))) void*)g,
                                     (__attribute__((address_space(3))) void*)lds,
                                     16, 0, 0);
}

// raw v_exp_f32 (2^x): args are provably in-range; skips libm denormal fixup.
__device__ __forceinline__ float fast_exp2(float x) {
    return __builtin_amdgcn_exp2f(x);
}

// 16x16x16 bf16 MFMA (K=16): A 2 VGPR / B 2 VGPR / C-D 4 (cdna4_isa §10).
// Builtin name differs across ROCm: prefer new-style, fall back to _1k (v4i16).
__device__ __forceinline__ f32x4 mfma16_bf16(bf16x4 a, bf16x4 b, f32x4 c) {
#if __has_builtin(__builtin_amdgcn_mfma_f32_16x16x16_bf16)
    return __builtin_amdgcn_mfma_f32_16x16x16_bf16(a, b, c, 0, 0, 0);
#else
    union U { bf16x4 h; s16x4 s; };
    U ua, ub; ua.h = a; ub.h = b;
    return __builtin_amdgcn_mfma_f32_16x16x16bf16_1k(ua.s, ub.s, c, 0, 0, 0);
#endif
}

// ---------------------------------------------------------------------------
// Tiled transpose+convert: W [K][N] fp32 -> WT [N][K] bf16 (dtype proven r3/4).
// ---------------------------------------------------------------------------
__global__ __launch_bounds__(256) void transpose_cvt_k(
    const float* __restrict__ W, bf16_t* __restrict__ WT, int K, int N) {
    __shared__ float tile[32][33];
    const int n0 = blockIdx.x * 32, k0 = blockIdx.y * 32;
    const int tx = threadIdx.x & 31, ty = threadIdx.x >> 5;   // ty 0..7
#pragma unroll
    for (int i = 0; i < 32; i += 8)
        tile[ty + i][tx] = W[(size_t)(k0 + ty + i) * N + (n0 + tx)];
    __syncthreads();
#pragma unroll
    for (int i = 0; i < 32; i += 8)
        WT[(size_t)(n0 + ty + i) * K + (k0 + tx)] = (bf16_t)tile[tx][ty + i];
}

// V transpose: Vb [bh][s][d] -> Vt [bh][d][s], LDS-tiled, both sides coalesced.
__global__ __launch_bounds__(256) void vtrans_k(const bf16_t* __restrict__ Vb,
                                                bf16_t* __restrict__ Vt) {
    __shared__ bf16_t tile[32][33];
    const int bh = blockIdx.z;
    const int s0 = blockIdx.y * 32;
    const int d0 = blockIdx.x * 32;
    const int tx = threadIdx.x & 31, ty = threadIdx.x >> 5;   // ty 0..7
    const bf16_t* src = Vb + ((size_t)bh * SEQ + s0) * HDIM + d0;
#pragma unroll
    for (int i = 0; i < 32; i += 8)
        tile[ty + i][tx] = src[(size_t)(ty + i) * HDIM + tx];
    __syncthreads();
    bf16_t* dst = Vt + ((size_t)bh * HDIM + d0) * SEQ + s0;
#pragma unroll
    for (int i = 0; i < 32; i += 8)
        dst[(size_t)(ty + i) * SEQ + tx] = tile[tx][ty + i];
}

// ---------------------------------------------------------------------------
// GEMM (unchanged from round 9): C[M][N] = A[M][K=768] * BT[N][K]^T + bias.
// MODE 1 (QKV): A fp32 ingest (register convert), B via global_load_lds;
//               bf16 [bh][s][d] out; Q pre-scaled by QSCALE.
// MODE 0 (proj): A bf16 via global_load_lds; fp32 out.
// ---------------------------------------------------------------------------
template<int MODE>
__global__ __launch_bounds__(256) void gemm_kernel(
    const void* __restrict__ Av,
    const bf16_t* __restrict__ BT,
    const float* __restrict__ bias,
    float* __restrict__ out,
    bf16_t* __restrict__ qbuf,
    bf16_t* __restrict__ kbuf,
    bf16_t* __restrict__ vbuf,
    int Ncols)
{
    const int K = 768;
    __shared__ alignas(16) bf16_t As[2][128 * 32];
    __shared__ alignas(16) bf16_t Bs[2][128 * 32];

    const int tid    = threadIdx.x;
    const int wave   = tid >> 6;
    const int lane   = tid & 63;
    const int lane15 = lane & 15;
    const int quad   = lane >> 4;

    const int mBase = blockIdx.y * 128;
    const int nBase = blockIdx.x * 128;
    const int wm = (wave >> 1) * 64;
    const int wn = (wave & 1) * 64;

    f32x4 acc[4][4];
#pragma unroll
    for (int i = 0; i < 4; i++)
#pragma unroll
        for (int j = 0; j < 4; j++) acc[i][j] = (f32x4){0.f, 0.f, 0.f, 0.f};

    const bf16_t* bSrc = BT + (size_t)nBase * K;

    const int srow = lane >> 2;      // 0..15 within 16-row group
    const int sch  = lane & 3;       // physical chunk this lane fills

    auto issueB = [&](int k0, int buf) {
#pragma unroll
        for (int p = 0; p < 2; p++) {
            int r0  = p * 64 + wave * 16;          // wave-uniform
            int row = r0 + srow;
            int lch = sch ^ (row & 3);             // logical chunk to fetch
            gld_lds16(&Bs[buf][r0 * 32], bSrc + (size_t)row * K + k0 + lch * 8);
        }
    };

    const int arow  = tid >> 1;          // 0..127
    const int ahalf = tid & 1;           // 16-col half
    float4 afr[4];
    const float*  aSrcF = (MODE == 1) ? (const float*)Av + (size_t)mBase * K : nullptr;
    const bf16_t* aSrcB = (MODE == 0) ? (const bf16_t*)Av + (size_t)mBase * K : nullptr;

    auto loadA = [&](int k0) {
        if (MODE == 1) {
            const float* p = aSrcF + (size_t)arow * K + k0 + ahalf * 16;
#pragma unroll
            for (int q = 0; q < 4; q++) afr[q] = *(const float4*)(p + q * 4);
        }
    };
    auto writeA = [&](int buf) {
#pragma unroll
        for (int c = 0; c < 2; c++) {
            bf16x8 v;
#pragma unroll
            for (int e = 0; e < 8; e++) {
                float f = (e < 4) ? ((const float*)&afr[c * 2])[e]
                                  : ((const float*)&afr[c * 2 + 1])[e - 4];
                v[e] = (bf16_t)f;
            }
            int lch = ahalf * 2 + c;
            *(bf16x8*)&As[buf][arow * 32 + (lch ^ (arow & 3)) * 8] = v;
        }
    };
    auto issueA0 = [&](int k0, int buf) {
#pragma unroll
        for (int p = 0; p < 2; p++) {
            int r0  = p * 64 + wave * 16;
            int row = r0 + srow;
            int lch = sch ^ (row & 3);
            gld_lds16(&As[buf][r0 * 32], aSrcB + (size_t)row * K + k0 + lch * 8);
        }
    };

    if (MODE == 1) { loadA(0); issueB(0, 0); writeA(0); }
    else           { issueA0(0, 0); issueB(0, 0); }

    for (int k0 = 0, it = 0; k0 < K; k0 += 32, it++) {
        const int buf = it & 1;
        __syncthreads();
        const bool more = (k0 + 32 < K);
        if (more) {
            issueB(k0 + 32, buf ^ 1);
            if (MODE == 1) loadA(k0 + 32); else issueA0(k0 + 32, buf ^ 1);
        }

        bf16x8 aF[4], bF[4];
#pragma unroll
        for (int t = 0; t < 4; t++) {
            int ra = wm + t * 16 + lane15;
            int rb = wn + t * 16 + lane15;
            aF[t] = *(const bf16x8*)&As[buf][ra * 32 + (quad ^ (ra & 3)) * 8];
            bF[t] = *(const bf16x8*)&Bs[buf][rb * 32 + (quad ^ (rb & 3)) * 8];
        }
#pragma unroll
        for (int i = 0; i < 4; i++)
#pragma unroll
            for (int j = 0; j < 4; j++)
                acc[i][j] = __builtin_amdgcn_mfma_f32_16x16x32_bf16(aF[i], bF[j], acc[i][j], 0, 0, 0);

        if (MODE == 1 && more) writeA(buf ^ 1);
    }

    const int region = (MODE == 1) ? (nBase / EMB) : 0;
    bf16_t* dst = nullptr;
    float scale = 1.0f;
    if (MODE == 1) {
        dst = (region == 0) ? qbuf : (region == 1 ? kbuf : vbuf);
        if (region == 0) scale = QSCALE;
    }
#pragma unroll
    for (int i = 0; i < 4; i++) {
#pragma unroll
        for (int j = 0; j < 4; j++) {
            int gn = nBase + wn + j * 16 + lane15;
            float bv = bias[gn];
#pragma unroll
            for (int r = 0; r < 4; r++) {
                int gm = mBase + wm + i * 16 + quad * 4 + r;
                float v = acc[i][j][r] + bv;
                if (MODE == 0) {
                    out[(size_t)gm * Ncols + gn] = v;      // FP32 store
                } else {
                    int b = gm >> 11, s = gm & 2047;
                    int within = gn - region * EMB;
                    int h = within >> 6, d = within & 63;
                    int bh = b * NHEAD + h;
                    dst[((size_t)bh * SEQ + s) * HDIM + d] = (bf16_t)(v * scale);
                }
            }
        }
    }
}

// ---------------------------------------------------------------------------
// Flash attention, causal — round 12: TRANSPOSED SCORES, no P LDS round-trip.
//  * S^T = mfma(A=K_frag, B=Q_frag): same loads as r8, operands swapped.
//    C-layout of S^T (key=quad*4+r, query=lane15) IS the B-operand layout of
//    v_mfma_f32_16x16x16_bf16 -> P^T goes exp2 -> bf16 pack -> straight into
//    PV MFMAs. The per-key-tile LDS round-trip (16 ds_write + lgkm drain +
//    2 ds_read_b128, the serial chain) is DELETED.
//  * PV: O^T[d][q] += V^T_frag(A, ds_read_b64 from Vs) * P^T(B). O^T is
//    un-transposed ONCE per q-tile via per-wave LDS.
//  * Everything else = r8 exactly: grid 768 paired {j,31-j} (uniform 33
//    tiles/block), plain launch_bounds(256) (r10/r11 caps caused spills),
//    K+V global_load_lds dbuf, diagonal-only mask, unnormalized exp2 softmax.
// ---------------------------------------------------------------------------
__global__ __launch_bounds__(256) void attn_kernel(
    const bf16_t* __restrict__ qbuf,
    const bf16_t* __restrict__ kbuf,
    const bf16_t* __restrict__ vtbuf,
    bf16_t* __restrict__ obuf)
{
    __shared__ alignas(16) bf16_t Ks[2][64 * 64];     // [key][dim], dbuf 16 KB
    __shared__ alignas(16) bf16_t Vs[2][64 * 64];     // [dim][key], dbuf 16 KB
    __shared__ alignas(16) bf16_t Plds[4][16 * 72];   // per-wave O-transpose scratch

    const int tid    = threadIdx.x;
    const int wave   = tid >> 6;
    const int lane   = tid & 63;
    const int lane15 = lane & 15;
    const int quad   = lane >> 4;

    const int bh = blockIdx.x >> 4;
    const int j  = blockIdx.x & 15;

    const bf16_t* Qp = qbuf  + (size_t)bh * SEQ * HDIM;
    const bf16_t* Kp = kbuf  + (size_t)bh * SEQ * HDIM;
    const bf16_t* Vp = vtbuf + (size_t)bh * HDIM * SEQ;
    bf16_t* pl = &Plds[wave][0];
    const int b = bh / NHEAD, h = bh % NHEAD;

    const int srow8 = lane >> 3;   // 0..7 within 8-row group
    const int sch8  = lane & 7;    // physical chunk this lane fills

    auto issueKV = [&](int kb, int buf) {
#pragma unroll
        for (int p = 0; p < 2; p++) {
            int r0  = p * 32 + wave * 8;             // wave-uniform
            int row = r0 + srow8;
            int lch = sch8 ^ (row & 7);              // logical chunk to fetch
            gld_lds16(&Ks[buf][r0 * 64], Kp + (size_t)(kb + row) * HDIM + lch * 8);
            gld_lds16(&Vs[buf][r0 * 64], Vp + (size_t)row * SEQ + kb + lch * 8);
        }
    };

    for (int seg = 0; seg < 2; seg++) {
        const int qt = seg ? (31 - j) : j;
        const int q0 = qt * 64 + wave * 16;

        // Q fragments (same data as r8; used as B-operand now)
        const bf16x8 qf0 = *(const bf16x8*)&Qp[(size_t)(q0 + lane15) * HDIM + quad * 8];
        const bf16x8 qf1 = *(const bf16x8*)&Qp[(size_t)(q0 + lane15) * HDIM + 32 + quad * 8];

        float lrow = 0.f;                 // per-lane partial l for query=lane15
        f32x4 oT[4];                      // O^T: d = t*16+quad*4+r, q = lane15
#pragma unroll
        for (int t = 0; t < 4; t++) oT[t] = (f32x4){0.f, 0.f, 0.f, 0.f};

        const int nT = qt + 1;    // 64-key tiles
        __syncthreads();          // protect buffers from previous seg's readers
        issueKV(0, 0);

        for (int kt = 0; kt < nT; kt++) {
            const int buf = kt & 1;
            __syncthreads();                                   // tile kt ready
            if (kt + 1 < nT) issueKV((kt + 1) * 64, buf ^ 1);  // prefetch

            const int kb = kt * 64;

            // QK^T -> S^T[key][query]: A = K fragment, B = Q fragment
            f32x4 sT[4];
#pragma unroll
            for (int kg = 0; kg < 4; kg++) {
                sT[kg] = (f32x4){0.f, 0.f, 0.f, 0.f};
                int row = kg * 16 + lane15;
                bf16x8 kf0 = *(const bf16x8*)&Ks[buf][row * 64 + ((quad    ) ^ (row & 7)) * 8];
                bf16x8 kf1 = *(const bf16x8*)&Ks[buf][row * 64 + ((quad + 4) ^ (row & 7)) * 8];
                sT[kg] = __builtin_amdgcn_mfma_f32_16x16x32_bf16(kf0, qf0, sT[kg], 0, 0, 0);
                sT[kg] = __builtin_amdgcn_mfma_f32_16x16x32_bf16(kf1, qf1, sT[kg], 0, 0, 0);
            }

            // causal mask: only the diagonal tile (wave-uniform test)
            if (kb + 64 > q0) {
                const int query = q0 + lane15;
#pragma unroll
                for (int kg = 0; kg < 4; kg++) {
                    int key0 = kb + kg * 16 + quad * 4;
#pragma unroll
                    for (int r = 0; r < 4; r++)
                        sT[kg][r] = (key0 + r <= query) ? sT[kg][r] : -1e30f;
                }
            }

            // unnormalized softmax: P^T = exp2(S^T); l += sum; pack to bf16
            bf16x4 pf[4];
#pragma unroll
            for (int kg = 0; kg < 4; kg++) {
#pragma unroll
                for (int r = 0; r < 4; r++) sT[kg][r] = fast_exp2(sT[kg][r]);
                lrow += (sT[kg][0] + sT[kg][1]) + (sT[kg][2] + sT[kg][3]);
                bf16x4 v;
#pragma unroll
                for (int r = 0; r < 4; r++) v[r] = (bf16_t)sT[kg][r];
                pf[kg] = v;
            }

            // PV: O^T[d][q] += V^T[d][k] * P^T[k][q], 16x16x16 MFMAs.
            // A-frag: 8 B from Vs row (t*16+lane15), keys kg*16+quad*4..+3.
#pragma unroll
            for (int t = 0; t < 4; t++) {
                int vrow = t * 16 + lane15;
#pragma unroll
                for (int kg = 0; kg < 4; kg++) {
                    int c    = kg * 2 + (quad >> 1);           // logical 8-elem chunk
                    int phys = c ^ (vrow & 7);
                    bf16x4 vf = *(const bf16x4*)&Vs[buf][vrow * 64 + phys * 8 + (quad & 1) * 4];
                    oT[t] = mfma16_bf16(vf, pf[kg], oT[t]);
                }
            }
        }

        // l: sum the 4 quads holding this query column (2 shuffles)
        lrow += __shfl_xor(lrow, 16, 64);
        lrow += __shfl_xor(lrow, 32, 64);
        const float inv = 1.0f / lrow;

        // O^T -> LDS (per-wave) -> coalesced global write, once per q-tile
#pragma unroll
        for (int t = 0; t < 4; t++)
#pragma unroll
            for (int r = 0; r < 4; r++)
                pl[lane15 * 72 + t * 16 + quad * 4 + r] = (bf16_t)(oT[t][r] * inv);

        const int qrow = lane >> 2;      // 0..15 query within tile
        const int ch   = lane & 3;       // 8-elem d-chunk
        bf16_t* orow = &obuf[((size_t)(b * SEQ + q0 - wave * 16 + wave * 16 + qrow)) * EMB + h * HDIM];
        // (q0 already includes wave*16; qrow indexes within this wave's 16 queries)
        orow = &obuf[((size_t)(b * SEQ + q0 + qrow)) * EMB + h * HDIM];
#pragma unroll
        for (int p = 0; p < 2; p++) {
            bf16x8 v = *(const bf16x8*)&pl[qrow * 72 + (ch + p * 4) * 8];
            *(bf16x8*)&orow[(ch + p * 4) * 8] = v;
        }
    }
}

// ---------------------------------------------------------------------------
extern "C" void kernel_launch(void* const* d_in, const int* in_sizes, int n_in,
                              void* d_out, int out_size, void* d_ws, size_t ws_size,
                              hipStream_t stream) {
    const float* x      = (const float*)d_in[0];
    // d_in[1] = mask: causal by construction, implemented analytically
    const float* W_attn = (const float*)d_in[2];
    const float* b_attn = (const float*)d_in[3];
    const float* W_proj = (const float*)d_in[4];
    const float* b_proj = (const float*)d_in[5];
    float* out = (float*)d_out;   // fp32 output (proven r4)

    bf16_t* ws  = (bf16_t*)d_ws;
    bf16_t* WaT = ws;                                         // [2304][768]
    bf16_t* WpT = WaT + (size_t)N3 * EMB;                     // [768][768]
    bf16_t* Qb  = WpT + (size_t)EMB * EMB;                    // [B*H][S][D]
    bf16_t* Kb  = Qb + (size_t)BATCH * NHEAD * SEQ * HDIM;
    bf16_t* Vt  = Kb + (size_t)BATCH * NHEAD * SEQ * HDIM;    // [B*H][D][S]
    bf16_t* Ob  = Vt + (size_t)BATCH * NHEAD * SEQ * HDIM;    // [8192][768]
    bf16_t* Vb  = Ob;   // alias: V [bh][s][d] staging dead before attn writes Ob

    transpose_cvt_k<<<dim3(N3 / 32, EMB / 32), 256, 0, stream>>>(W_attn, WaT, EMB, N3);
    transpose_cvt_k<<<dim3(EMB / 32, EMB / 32), 256, 0, stream>>>(W_proj, WpT, EMB, EMB);

    gemm_kernel<1><<<dim3(N3 / 128, MROWS / 128), 256, 0, stream>>>(
        x, WaT, b_attn, nullptr, Qb, Kb, Vb, N3);

    vtrans_k<<<dim3(HDIM / 32, SEQ / 32, BATCH * NHEAD), 256, 0, stream>>>(Vb, Vt);

    attn_kernel<<<BATCH * NHEAD * 16, 256, 0, stream>>>(Qb, Kb, Vt, Ob);

    gemm_kernel<0><<<dim3(EMB / 128, MROWS / 128), 256, 0, stream>>>(
        Ob, WpT, b_proj, out, nullptr, nullptr, nullptr, EMB);
}